// Round 5
// baseline (33.776 us; speedup 1.0000x reference)
//
#include <hip/hip_runtime.h>
#include <math.h>

#define NN 64
#define HH 256
#define LL 2048
#define INV_L (1.0f / 2048.0f)
#define PADIDX(a) ((a) + ((a) >> 4))

__device__ __forceinline__ float rlane(float v, int l) {
  return __int_as_float(__builtin_amdgcn_readlane(__float_as_int(v), l));
}

// ---------------------------------------------------------------------------
// One block per h (grid 256, block 1024).
//  Phase A: thread tid computes spectrum bin m=tid. Per-n constants live in
//           lane-n registers, broadcast via v_readlane (VALU pipe; LDS pipe
//           was the R3 bottleneck).
//  Phase B: radix-2 DIF inverse FFT in LDS; stages 11..8 barrier-synced,
//           stages 7..1 wave-private (each wave owns a 128-elem segment).
//  Phase C: bit-reversed gather, coalesced store.
//
// Algebra (z = iu, u = 2*tan(t/2), omega=e^{-it}, 2/(1+omega) = 1+i*tau):
//  i1 = 1/(z-w):  Re=-wre/n1, Im=-(u-wim)/n1,  n1=(u-wim)^2+wre^2  (DIRECT —
//  i2 = 1/(z-cw): Re=-wre/n2, Im=-(u+wim)/n2,  n2=(u+wim)^2+wre^2   the R4
//  s^2-p^2 form catastrophically cancelled at resonance u~wim: reverted.)
//  q = 1/(n1*n2):
//   A  = Re(i1)+Re(i2) = -wre*(n1+n2)*q
//   D  = Re(i1)-Re(i2) = -wre*(n2-n1)*q = -wre*4u*wim*q   (exact diff form)
//   Bc = Im(i2)-Im(i1) = 2wim*(u^2-|w|^2)*q
//   Cc = Im(i1)+Im(i2) = -2u*(u^2+wre^2-wim^2)*q
// ---------------------------------------------------------------------------
__global__ __launch_bounds__(1024) void fused_kernel(
    const float* __restrict__ C_ri, const float* __restrict__ B_ri,
    const float* __restrict__ P_ri, const float* __restrict__ Q_ri,
    const float* __restrict__ w_ri, const float* __restrict__ log_dt,
    float* __restrict__ out)
{
  const int h   = blockIdx.x;
  const int tid = threadIdx.x;
  const int lane = tid & 63;

  __shared__ float2 X[2176];                    // 2048 + pad, max idx 2174
  __shared__ float4 sKA[NN], sKB[NN], sKC[NN];

  const float dt = expf(log_dt[h]);

  if (tid < NN) {              // wave 0: build per-n constants
    const float2 b = reinterpret_cast<const float2*>(B_ri)[h*NN + tid];
    const float2 c = reinterpret_cast<const float2*>(C_ri)[h*NN + tid];
    const float2 p = reinterpret_cast<const float2*>(P_ri)[h*NN + tid];
    const float2 q = reinterpret_cast<const float2*>(Q_ri)[h*NN + tid];
    const float2 w = reinterpret_cast<const float2*>(w_ri)[h*NN + tid];
    const float wre = w.x * dt, wim = w.y * dt;
    // (wim, wre^2, |w|^2, -wre)
    sKA[tid] = make_float4(wim, wre*wre, fmaf(wre,wre,wim*wim), -wre);
    const float v00r = b.x*c.x - b.y*c.y;
    sKB[tid] = make_float4(v00r, b.x*c.y + b.y*c.x,
                           b.x*q.x - b.y*q.y, b.x*q.y + b.y*q.x);
    sKC[tid] = make_float4(p.x*c.x - p.y*c.y, p.x*c.y + p.y*c.x,
                           p.x*q.x - p.y*q.y, p.x*q.y + p.y*q.x);
    // Nyquist bin: lim_{tau->inf} k_f = dt * Re(sum_n B_n C_n)
    float s = v00r;
    #pragma unroll
    for (int off = 32; off; off >>= 1) s += __shfl_xor(s, off, 64);
    if (tid == 0) X[PADIDX(1024)] = make_float2(dt * s * INV_L, 0.f);
  }
  __syncthreads();

  // Every wave: pull the per-n constant tables into lane registers (12 VGPRs).
  const float4 kA = sKA[lane];
  const float4 kB = sKB[lane];
  const float4 kC = sKC[lane];

  // ---- Phase A: one spectrum bin per thread (m = tid, 0..1023) ----
  {
    const int m = tid;
    const float rev = (float)m * (1.0f / 4096.0f);          // exact dyadic
    const float sn  = __builtin_amdgcn_sinf(rev);           // sin(2*pi*rev)
    const float cs  = __builtin_amdgcn_cosf(rev);           // cos(2*pi*rev)
    const float tau = sn * __builtin_amdgcn_rcpf(cs);       // tan(t/2) >= 0
    const float u   = tau + tau;
    const float u2  = u * u;
    const float u2x = u + u;
    const float u4  = u2x + u2x;

    float r00r=0.f, r00i=0.f, r01r=0.f, r01i=0.f;
    float r10r=0.f, r10i=0.f, r11r=0.f, r11i=0.f;

    #pragma unroll 4
    for (int n = 0; n < NN; ++n) {
      const float Wim = rlane(kA.x, n);         // wim
      const float Wr2 = rlane(kA.y, n);         // wre^2
      const float Ww2 = rlane(kA.z, n);         // |w|^2
      const float Wnr = rlane(kA.w, n);         // -wre
      const float d1 = u - Wim;
      const float d2 = u + Wim;
      const float n1 = fmaf(d1, d1, Wr2);       // |z-w|^2      (stable)
      const float n2 = fmaf(d2, d2, Wr2);       // |z-conj w|^2 (stable)
      const float q  = __builtin_amdgcn_rcpf(n1 * n2);
      const float A  = Wnr * ((n1 + n2) * q);
      const float pq = (u4 * Wim) * q;          // (n2-n1)*q, exact form
      const float D  = Wnr * pq;
      const float t0 = u2 - Ww2;                // u^2 - |w|^2
      const float E1 = (Wim + Wim) * (t0 * q);  // Bc
      const float e2c = fmaf(2.0f, Wr2, t0);    // u^2 + wre^2 - wim^2
      const float E2 = u2x * (e2c * q);         // -Cc
      const float v00r = rlane(kB.x, n), v00i = rlane(kB.y, n);
      const float v01r = rlane(kB.z, n), v01i = rlane(kB.w, n);
      const float v10r = rlane(kC.x, n), v10i = rlane(kC.y, n);
      const float v11r = rlane(kC.z, n), v11i = rlane(kC.w, n);
      r00r = fmaf(v00r, A, r00r);   r00r = fmaf(v00i, E1, r00r);
      r00i = fmaf(v00r, -E2, r00i); r00i = fmaf(v00i, D, r00i);
      r01r = fmaf(v01r, A, r01r);   r01r = fmaf(v01i, E1, r01r);
      r01i = fmaf(v01r, -E2, r01i); r01i = fmaf(v01i, D, r01i);
      r10r = fmaf(v10r, A, r10r);   r10r = fmaf(v10i, E1, r10r);
      r10i = fmaf(v10r, -E2, r10i); r10i = fmaf(v10i, D, r10i);
      r11r = fmaf(v11r, A, r11r);   r11r = fmaf(v11i, E1, r11r);
      r11i = fmaf(v11r, -E2, r11i); r11i = fmaf(v11i, D, r11i);
    }
    r00r *= dt; r00i *= dt; r01r *= dt; r01i *= dt;
    r10r *= dt; r10i *= dt; r11r *= dt; r11i *= dt;

    // Woodbury: kf = r00 - r01*r10/(1+r11)
    const float opr = 1.0f + r11r, opi = r11i;
    const float numr = r01r*r10r - r01i*r10i;
    const float numi = r01r*r10i + r01i*r10r;
    const float qd = __builtin_amdgcn_rcpf(fmaf(opr,opr,opi*opi));
    const float cr = (numr*opr + numi*opi) * qd;
    const float ci = (numi*opr - numr*opi) * qd;
    const float ar = r00r - cr, ai = r00i - ci;
    // * (1 + i*tau), * 1/L
    const float orr = fmaf(-ai, tau, ar) * INV_L;
    const float oii = fmaf( ar, tau, ai) * INV_L;

    if (m == 0) {
      X[PADIDX(0)] = make_float2(orr, 0.f);               // DC imag dropped
    } else {
      X[PADIDX(m)]      = make_float2(orr, oii);
      X[PADIDX(LL - m)] = make_float2(orr, -oii);         // hermitian mirror
    }
  }
  __syncthreads();

  // ---- Phase B: radix-2 DIF inverse FFT, W = e^{+2*pi*i*j/len} ----
  // Stages 11..8: cross-wave spans -> block barrier after each.
  // Stages 7..1: butterfly group of wave w stays inside X[128w .. 128w+128)
  //              -> same-wave lgkmcnt ordering suffices, no barrier.
  for (int s = 11; s >= 1; --s) {
    const int half = 1 << (s - 1);
    const float invlen = 1.0f / (float)(1 << s);          // exact pow2
    const int i  = tid;
    const int j  = i & (half - 1);
    const int i0 = ((i >> (s - 1)) << s) + j;
    const int i1 = i0 + half;
    const float2 u = X[PADIDX(i0)];
    const float2 v = X[PADIDX(i1)];
    const float rev = (float)j * invlen;                  // exact dyadic
    const float wc = __builtin_amdgcn_cosf(rev);
    const float ws = __builtin_amdgcn_sinf(rev);
    const float dx = u.x - v.x, dy = u.y - v.y;
    X[PADIDX(i0)] = make_float2(u.x + v.x, u.y + v.y);
    X[PADIDX(i1)] = make_float2(fmaf(dx, wc, -dy * ws),
                                fmaf(dx, ws,  dy * wc));
    if (s >= 8) __syncthreads();
  }
  __syncthreads();

  // ---- Phase C: bit-reversed gather, coalesced store ----
  #pragma unroll
  for (int c = 0; c < 2; ++c) {
    const int n = tid + (c << 10);
    const int p = (int)(__brev((unsigned)n) >> 21);       // bitrev11
    const float v = X[PADIDX(p)].x;                       // pre-scaled by 1/L
    out[h*LL + n] = isfinite(v) ? v : 0.0f;               // nan_to_num
  }
}

extern "C" void kernel_launch(void* const* d_in, const int* in_sizes, int n_in,
                              void* d_out, int out_size, void* d_ws, size_t ws_size,
                              hipStream_t stream) {
  (void)in_sizes; (void)n_in; (void)out_size; (void)d_ws; (void)ws_size;
  const float* C_ri  = (const float*)d_in[0];
  const float* B_ri  = (const float*)d_in[1];
  const float* P_ri  = (const float*)d_in[2];
  const float* Q_ri  = (const float*)d_in[3];
  const float* w_ri  = (const float*)d_in[4];
  const float* logdt = (const float*)d_in[5];

  fused_kernel<<<HH, 1024, 0, stream>>>(C_ri, B_ri, P_ri, Q_ri, w_ri, logdt,
                                        (float*)d_out);
}

// Round 6
// 23.056 us; speedup vs baseline: 1.4650x; 1.4650x over previous
//
#include <hip/hip_runtime.h>
#include <math.h>

#define NN 64
#define HH 256
#define LL 2048
#define INV_L (1.0f / 2048.0f)
#define PADIDX(a) ((a) + ((a) >> 4))
#define REC_F 12                      // floats per (h,n) record
#define HTAB_F (NN * REC_F)           // 768 floats per h
#define NYQ_OFF (HH * HTAB_F)         // float offset of nyq[] in kTab

// ---------------------------------------------------------------------------
// Prep kernel (grid HH, block 64): per (h,n) constants for the PAIR form
//   v/(z-w) + conj(v)/(z-conj w) = (a + i*b*u) / (dr + i*di),
//   dr = |w|^2 - u^2, di = -2*wre*u,
//   a_ab = -2*dt*(vab_r*wre + vab_i*wim),  b_ab = 2*dt*vab_r   (dt folded).
// Record: {a00,b00,a01,b01, a10,b10,a11,b11, |w|^2, -2wre, 0,0}.
// Also nyq[h] = lim k_f[1024] * 1/L = dt*sum Re(B*C) / L  (wave reduce).
// ---------------------------------------------------------------------------
__global__ __launch_bounds__(64) void prep_kernel(
    const float* __restrict__ C_ri, const float* __restrict__ B_ri,
    const float* __restrict__ P_ri, const float* __restrict__ Q_ri,
    const float* __restrict__ w_ri, const float* __restrict__ log_dt,
    float* __restrict__ kTab)
{
  const int h = blockIdx.x;
  const int n = threadIdx.x;
  const float dt = expf(log_dt[h]);

  const float2 b = reinterpret_cast<const float2*>(B_ri)[h*NN + n];
  const float2 c = reinterpret_cast<const float2*>(C_ri)[h*NN + n];
  const float2 p = reinterpret_cast<const float2*>(P_ri)[h*NN + n];
  const float2 q = reinterpret_cast<const float2*>(Q_ri)[h*NN + n];
  const float2 w = reinterpret_cast<const float2*>(w_ri)[h*NN + n];
  const float wre = w.x * dt, wim = w.y * dt;

  const float v00r = b.x*c.x - b.y*c.y, v00i = b.x*c.y + b.y*c.x;  // B*C
  const float v01r = b.x*q.x - b.y*q.y, v01i = b.x*q.y + b.y*q.x;  // B*Q
  const float v10r = p.x*c.x - p.y*c.y, v10i = p.x*c.y + p.y*c.x;  // P*C
  const float v11r = p.x*q.x - p.y*q.y, v11i = p.x*q.y + p.y*q.x;  // P*Q

  const float m2dt = -2.0f * dt, p2dt = 2.0f * dt;
  float4* rec = reinterpret_cast<float4*>(kTab + (size_t)h*HTAB_F + n*REC_F);
  rec[0] = make_float4(m2dt*fmaf(v00r,wre,v00i*wim), p2dt*v00r,
                       m2dt*fmaf(v01r,wre,v01i*wim), p2dt*v01r);
  rec[1] = make_float4(m2dt*fmaf(v10r,wre,v10i*wim), p2dt*v10r,
                       m2dt*fmaf(v11r,wre,v11i*wim), p2dt*v11r);
  rec[2] = make_float4(fmaf(wre,wre,wim*wim), -2.0f*wre, 0.f, 0.f);

  float s = v00r;                        // Nyquist: dt*sum Re(B*C) / L
  #pragma unroll
  for (int off = 32; off; off >>= 1) s += __shfl_xor(s, off, 64);
  if (n == 0) kTab[NYQ_OFF + h] = dt * s * INV_L;
}

// ---------------------------------------------------------------------------
// Fused kernel: one block per h (grid 256, block 1024).
//  Phase A: thread tid computes spectrum bin m=tid using the pair form.
//           Constants come from kTab via UNIFORM address (blockIdx + loop
//           index) -> scalar s_load path: LDS pipe (the R3 bottleneck) and
//           readlane (the R5 mistake) both avoided; each fma uses the
//           constant as its single SGPR operand.
//  Phase B: radix-2 DIF inverse FFT in LDS; stages 11..8 barrier-synced,
//           stages 7..1 wave-private (wave w owns X[128w..128w+128)).
//  Phase C: bit-reversed gather, coalesced store.
// ---------------------------------------------------------------------------
__global__ __launch_bounds__(1024) void fused_kernel(
    const float* __restrict__ kTab, float* __restrict__ out)
{
  const int h   = blockIdx.x;
  const int tid = threadIdx.x;

  __shared__ float2 X[2176];                 // 2048 + pad, max idx 2174

  if (tid == 0) {
    X[PADIDX(1024)] = make_float2(kTab[NYQ_OFF + h], 0.f);
  }

  // ---- Phase A: one spectrum bin per thread (m = tid, 0..1023) ----
  {
    const float4* __restrict__ tab =
        reinterpret_cast<const float4*>(kTab + (size_t)h*HTAB_F);
    const int m = tid;
    const float rev = (float)m * (1.0f / 4096.0f);        // exact dyadic
    const float sn  = __builtin_amdgcn_sinf(rev);         // sin(2*pi*rev)
    const float cs  = __builtin_amdgcn_cosf(rev);         // cos(2*pi*rev)
    const float tau = sn * __builtin_amdgcn_rcpf(cs);     // tan(t/2) >= 0
    const float u   = tau + tau;
    const float u2  = u * u;

    float r00r=0.f, r00i=0.f, r01r=0.f, r01i=0.f;
    float r10r=0.f, r10i=0.f, r11r=0.f, r11i=0.f;

    #pragma unroll 4
    for (int n = 0; n < NN; ++n) {
      const float4 c0 = tab[n*3 + 0];        // a00,b00,a01,b01
      const float4 c1 = tab[n*3 + 1];        // a10,b10,a11,b11
      const float4 c2 = tab[n*3 + 2];        // |w|^2, -2wre, -, -
      const float dr  = c2.x - u2;
      const float di  = c2.y * u;
      const float den = fmaf(dr, dr, di*di); // sum of positives: stable
      const float qq  = __builtin_amdgcn_rcpf(den);
      const float drq = dr * qq,  diq  = di * qq;
      const float udrq = u * drq, udiq = u * diq;
      r00r = fmaf(c0.x, drq, r00r);  r00r = fmaf(c0.y, udiq, r00r);
      r00i = fmaf(c0.y, udrq, r00i); r00i = fmaf(-c0.x, diq, r00i);
      r01r = fmaf(c0.z, drq, r01r);  r01r = fmaf(c0.w, udiq, r01r);
      r01i = fmaf(c0.w, udrq, r01i); r01i = fmaf(-c0.z, diq, r01i);
      r10r = fmaf(c1.x, drq, r10r);  r10r = fmaf(c1.y, udiq, r10r);
      r10i = fmaf(c1.y, udrq, r10i); r10i = fmaf(-c1.x, diq, r10i);
      r11r = fmaf(c1.z, drq, r11r);  r11r = fmaf(c1.w, udiq, r11r);
      r11i = fmaf(c1.w, udrq, r11i); r11i = fmaf(-c1.z, diq, r11i);
    }
    // dt already folded into a,b.

    // Woodbury: kf = r00 - r01*r10/(1+r11)
    const float opr = 1.0f + r11r, opi = r11i;
    const float numr = r01r*r10r - r01i*r10i;
    const float numi = r01r*r10i + r01i*r10r;
    const float qd = __builtin_amdgcn_rcpf(fmaf(opr,opr,opi*opi));
    const float cr = (numr*opr + numi*opi) * qd;
    const float ci = (numi*opr - numr*opi) * qd;
    const float ar = r00r - cr, ai = r00i - ci;
    // * (1 + i*tau), * 1/L
    const float orr = fmaf(-ai, tau, ar) * INV_L;
    const float oii = fmaf( ar, tau, ai) * INV_L;

    if (m == 0) {
      X[PADIDX(0)] = make_float2(orr, 0.f);               // DC imag dropped
    } else {
      X[PADIDX(m)]      = make_float2(orr, oii);
      X[PADIDX(LL - m)] = make_float2(orr, -oii);         // hermitian mirror
    }
  }
  __syncthreads();

  // ---- Phase B: radix-2 DIF inverse FFT, W = e^{+2*pi*i*j/len} ----
  for (int s = 11; s >= 1; --s) {
    const int half = 1 << (s - 1);
    const float invlen = 1.0f / (float)(1 << s);          // exact pow2
    const int i  = tid;
    const int j  = i & (half - 1);
    const int i0 = ((i >> (s - 1)) << s) + j;
    const int i1 = i0 + half;
    const float2 u = X[PADIDX(i0)];
    const float2 v = X[PADIDX(i1)];
    const float rev = (float)j * invlen;                  // exact dyadic
    const float wc = __builtin_amdgcn_cosf(rev);
    const float ws = __builtin_amdgcn_sinf(rev);
    const float dx = u.x - v.x, dy = u.y - v.y;
    X[PADIDX(i0)] = make_float2(u.x + v.x, u.y + v.y);
    X[PADIDX(i1)] = make_float2(fmaf(dx, wc, -dy * ws),
                                fmaf(dx, ws,  dy * wc));
    if (s >= 8) __syncthreads();
  }
  __syncthreads();

  // ---- Phase C: bit-reversed gather, coalesced store ----
  #pragma unroll
  for (int c = 0; c < 2; ++c) {
    const int n = tid + (c << 10);
    const int p = (int)(__brev((unsigned)n) >> 21);       // bitrev11
    const float v = X[PADIDX(p)].x;                       // pre-scaled by 1/L
    out[h*LL + n] = isfinite(v) ? v : 0.0f;               // nan_to_num
  }
}

extern "C" void kernel_launch(void* const* d_in, const int* in_sizes, int n_in,
                              void* d_out, int out_size, void* d_ws, size_t ws_size,
                              hipStream_t stream) {
  (void)in_sizes; (void)n_in; (void)out_size; (void)ws_size;
  const float* C_ri  = (const float*)d_in[0];
  const float* B_ri  = (const float*)d_in[1];
  const float* P_ri  = (const float*)d_in[2];
  const float* Q_ri  = (const float*)d_in[3];
  const float* w_ri  = (const float*)d_in[4];
  const float* logdt = (const float*)d_in[5];
  float* kTab = (float*)d_ws;     // HH*768 + HH floats ~ 787 KB

  prep_kernel<<<HH, 64, 0, stream>>>(C_ri, B_ri, P_ri, Q_ri, w_ri, logdt, kTab);
  fused_kernel<<<HH, 1024, 0, stream>>>(kTab, (float*)d_out);
}